// Round 1
// 247.362 us; speedup vs baseline: 1.0023x; 1.0023x over previous
//
#include <hip/hip_runtime.h>
#include <math.h>

// Problem constants (N,T,V,M,n = 32,64,25,2,16)
#define NSAMP  32        // batch samples
#define BBATCH 3200      // matrices per sample (T*V*M)
#define NMAT   102400    // total matrices
#define ST     20        // LDS row stride: rows 16B-aligned, A-col reads 2-way banks (free)
#define IX(i,j) ((i)*ST+(j))
#define MSZ    (16*ST)

// workspace layout (float offsets)
#define PART_O 0         // 512*256 partial sums
#define WI_O   131072    // invsqrtm(mean) for centering

// Iteration counts. Spectra after trace-normalization are ~I +/- 0.03 here
// (means over 3200 matrices concentrate hard), so these have >=5x margin:
// NS residual 0.1 -> <1e-9 in 5 iters; log/exp Taylor err <= 0.1^8/8 ~ 1e-9.
#define NS_IT 5
#define LOG_M 7
#define EXP_M 6

// ---------------- wave-local 16x16 matrix helpers ----------------
// All helpers operate on ONE wave (64 lanes, lockstep). Lane l owns row
// i=l>>2, cols j0..j0+3 (j0=(l&3)*4). No __syncthreads: within a wave,
// cross-lane LDS visibility only needs the wave's own LDS ops drained.

__device__ __forceinline__ void wsync() {
  asm volatile("s_waitcnt lgkmcnt(0)" ::: "memory");
}

// C = A*B. C must not alias A or B.
__device__ __forceinline__ void wmm(const float* A, const float* B, float* C, int l) {
  int i = l >> 2, j0 = (l & 3) << 2;
  float4 acc = make_float4(0.f, 0.f, 0.f, 0.f);
  #pragma unroll
  for (int k = 0; k < 16; ++k) {
    float a = A[IX(i, k)];
    const float4 b = *(const float4*)&B[IX(k, j0)];
    acc.x += a * b.x; acc.y += a * b.y; acc.z += a * b.z; acc.w += a * b.w;
  }
  *(float4*)&C[IX(i, j0)] = acc;
  wsync();
}

// C = s*C + d*I  (per-lane read-modify-write, same address: in-order)
__device__ __forceinline__ void wmad_diag(float* C, float s, float d, int l) {
  int i = l >> 2, j0 = (l & 3) << 2;
  float4 p = *(float4*)&C[IX(i, j0)];
  p.x *= s; p.y *= s; p.z *= s; p.w *= s;
  if (i == j0) p.x += d; else if (i == j0 + 1) p.y += d;
  else if (i == j0 + 2) p.z += d; else if (i == j0 + 3) p.w += d;
  *(float4*)&C[IX(i, j0)] = p;
  wsync();
}

// C = d*I
__device__ __forceinline__ void wset_I(float* C, float d, int l) {
  int i = l >> 2, j0 = (l & 3) << 2;
  float4 p = make_float4(0.f, 0.f, 0.f, 0.f);
  if (i == j0) p.x = d; else if (i == j0 + 1) p.y = d;
  else if (i == j0 + 2) p.z = d; else if (i == j0 + 3) p.w = d;
  *(float4*)&C[IX(i, j0)] = p;
  wsync();
}

__device__ __forceinline__ void wsym(float* A, int l) {
  int i = l >> 2, j0 = (l & 3) << 2;
  float4 a = *(float4*)&A[IX(i, j0)];
  float4 v;
  v.x = 0.5f * (a.x + A[IX(j0,     i)]);
  v.y = 0.5f * (a.y + A[IX(j0 + 1, i)]);
  v.z = 0.5f * (a.z + A[IX(j0 + 2, i)]);
  v.w = 0.5f * (a.w + A[IX(j0 + 3, i)]);
  wsync();                              // all reads land before any write
  *(float4*)&A[IX(i, j0)] = v;
  wsync();
}

__device__ __forceinline__ float wtrace(const float* A) {
  float tr = 0.f;
  #pragma unroll
  for (int k = 0; k < 16; ++k) tr += A[IX(k, k)];
  return tr;
}

__device__ __forceinline__ void wcpy(const float* src, float* dst, int l) {
  int i = l >> 2, j0 = (l & 3) << 2;
  *(float4*)&dst[IX(i, j0)] = *(const float4*)&src[IX(i, j0)];
  wsync();
}

// Coupled Newton-Schulz sqrt/invsqrt. Input in Y0 (destroyed). 5 buffers.
__device__ void wns(float* Y0, float* Y1, float* Z0, float* Z1, float* P,
                    int l, float** pS, float** pZ) {
  float c = wtrace(Y0) * (1.f / 16.f);
  float ic = 1.f / c;
  int i = l >> 2, j0 = (l & 3) << 2;
  {
    float4 a = *(float4*)&Y0[IX(i, j0)];
    a.x *= ic; a.y *= ic; a.z *= ic; a.w *= ic;
    *(float4*)&Y0[IX(i, j0)] = a;
    float4 z = make_float4(0.f, 0.f, 0.f, 0.f);
    if (i == j0) z.x = 1.f; else if (i == j0 + 1) z.y = 1.f;
    else if (i == j0 + 2) z.z = 1.f; else if (i == j0 + 3) z.w = 1.f;
    *(float4*)&Z0[IX(i, j0)] = z;
  }
  wsync();
  float *Y = Y0, *Yn = Y1, *Z = Z0, *Zn = Z1;
  for (int it = 0; it < NS_IT; ++it) {
    wmm(Z, Y, P, l);                 // P = Z*Y
    wmad_diag(P, -0.5f, 1.5f, l);    // T = (3I - P)/2
    wmm(Y, P, Yn, l);
    wmm(P, Z, Zn, l);
    float* tp = Y; Y = Yn; Yn = tp;
    tp = Z; Z = Zn; Zn = tp;
  }
  float sc = sqrtf(c), isc = 1.f / sc;
  {
    float4 y = *(float4*)&Y[IX(i, j0)];
    y.x *= sc; y.y *= sc; y.z *= sc; y.w *= sc;
    *(float4*)&Y[IX(i, j0)] = y;
    float4 z = *(float4*)&Z[IX(i, j0)];
    z.x *= isc; z.y *= isc; z.z *= isc; z.w *= isc;
    *(float4*)&Z[IX(i, j0)] = z;
  }
  wsync();
  *pS = Y; *pZ = Z;
}

// L = log(S), S ~ I + E. S destroyed. L,R0,R1 distinct from S.
__device__ void wlog(float* S, float* L, float* R0, float* R1, int l) {
  wmad_diag(S, 1.f, -1.f, l);        // E = S - I
  float am = ((LOG_M & 1) ? 1.f : -1.f) / (float)LOG_M;
  wset_I(R0, am, l);
  float *R = R0, *Rn = R1;
  for (int j = LOG_M - 1; j >= 1; --j) {
    wmm(S, R, Rn, l);
    float aj = ((j & 1) ? 1.f : -1.f) / (float)j;
    wmad_diag(Rn, 1.f, aj, l);
    float* tp = R; R = Rn; Rn = tp;
  }
  wmm(S, R, L, l);
}

// exp(K), K preserved. Result lands in R0 (EXP_M even); returned by pointer.
__device__ float* wexp(const float* K, float* R0, float* R1, int l) {
  wset_I(R0, 1.f, l);
  float *R = R0, *Rn = R1;
  for (int j = EXP_M; j >= 1; --j) {
    wmm(K, R, Rn, l);
    wmad_diag(Rn, 1.f / (float)j, 1.f, l);
    float* tp = R; R = Rn; Rn = tp;
  }
  return R;
}

// ---------------- kernels ----------------

// Partial sums: 512 blocks = 32 samples x 16 chunks of 200 matrices.
// 512 threads (16 waves/CU at 2 blocks/CU) for latency hiding.
__global__ __launch_bounds__(512) void k_part(const float* __restrict__ X, float* __restrict__ ws) {
  int b = blockIdx.x >> 4;
  int c = blockIdx.x & 15;
  int t = threadIdx.x;
  int e4 = t & 63;
  int r  = t >> 6;                  // 0..7
  const float4* X4 = (const float4*)X;
  float4 s = make_float4(0.f, 0.f, 0.f, 0.f);
  long mbase = (long)b * BBATCH + c * 200;
  for (int i = r; i < 200; i += 8) {
    float4 v = X4[(mbase + i) * 64 + e4];
    s.x += v.x; s.y += v.y; s.z += v.z; s.w += v.w;
  }
  __shared__ float4 red[512];
  red[t] = s;
  __syncthreads();
  if (t < 64) {
    float4 o = red[t];
    #pragma unroll
    for (int k = 1; k < 8; ++k) {
      float4 v = red[t + 64 * k];
      o.x += v.x; o.y += v.y; o.z += v.z; o.w += v.w;
    }
    ((float4*)(ws + PART_O))[(long)blockIdx.x * 64 + t] = o;
  }
}

// Entire middle pipeline in ONE block (replaces k_xm/k_prep/k_logmap/k_mean2
// + the geodesic). 16 waves; all cross-stage data in LDS (~121 KB).
__global__ __launch_bounds__(1024) void k_mid(const float* __restrict__ rm,
                                              float* __restrict__ ws,
                                              float* __restrict__ out) {
  __shared__ __align__(16) float XmL[NSAMP * 256];   // sample means, then log-maps
  __shared__ __align__(16) float wb[16][4 * MSZ];    // 4 strided buffers per wave
  __shared__ __align__(16) float GsL[MSZ], GiL[MSZ], RsL[MSZ], RiL[MSZ], meanL[MSZ];
  int t = threadIdx.x;
  int w = t >> 6, l = t & 63;

  // --- A: per-sample means from partial sums (0.5 MB read, all threads) ---
  for (int idx = t; idx < NSAMP * 256; idx += 1024) {
    int b = idx >> 8, e = idx & 255;
    float s = 0.f;
    #pragma unroll
    for (int c = 0; c < 16; ++c) s += ws[PART_O + (b * 16 + c) * 256 + e];
    XmL[idx] = s * (1.f / BBATCH);
  }
  __syncthreads();

  // --- A2: G = mean_b(Xm) -> wb[0] (strided); rm -> wb[1] (strided) ---
  if (t < 256) {
    int i = t >> 4, j = t & 15;
    float s = 0.f;
    #pragma unroll
    for (int b = 0; b < NSAMP; ++b) s += XmL[b * 256 + t];
    wb[0][IX(i, j)] = s * (1.f / NSAMP);
  } else if (t < 512) {
    int e = t - 256, i = e >> 4, j = e & 15;
    wb[1][IX(i, j)] = rm[e];
  }
  __syncthreads();

  // --- B: NS(G) on wave0 and NS(rm) on wave1, concurrently ---
  if (w == 0) {
    float *S, *Z;
    wns(&wb[0][0], &wb[0][MSZ], &wb[0][2*MSZ], &wb[0][3*MSZ], &wb[2][0], l, &S, &Z);
    wcpy(S, GsL, l); wcpy(Z, GiL, l);
  } else if (w == 1) {
    float *S, *Z;
    wns(&wb[1][0], &wb[1][MSZ], &wb[1][2*MSZ], &wb[1][3*MSZ], &wb[3][0], l, &S, &Z);
    wcpy(S, RsL, l); wcpy(Z, RiL, l);
  }
  __syncthreads();

  // --- C: 32 log-maps, 16 waves x 2 rounds. L[b] overwrites XmL[b]. ---
  {
    float* B0 = &wb[w][0];       float* B1 = &wb[w][MSZ];
    float* B2 = &wb[w][2 * MSZ]; float* B3 = &wb[w][3 * MSZ];
    int i = l >> 2, j0 = (l & 3) << 2;
    for (int r = 0; r < 2; ++r) {
      int b = w + r * 16;
      *(float4*)&B0[IX(i, j0)] = *(const float4*)&XmL[b * 256 + i * 16 + j0];
      wsync();
      wmm(GiL, B0, B1, l);             // T = Gi*Xb
      wmm(B1, GiL, B2, l);             // S = Gi*Xb*Gi
      wsym(B2, l);
      wlog(B2, B3, B0, B1, l);         // L = B3 (S destroyed; B0,B1 scratch)
      *(float4*)&XmL[b * 256 + i * 16 + j0] = *(const float4*)&B3[IX(i, j0)];
      wsync();
    }
  }
  __syncthreads();

  // --- D: Lbar -> wb[0]; then mean = Gs*exp(Lbar)*Gs on wave0 ---
  if (t < 256) {
    int i = t >> 4, j = t & 15;
    float s = 0.f;
    #pragma unroll
    for (int b = 0; b < NSAMP; ++b) s += XmL[b * 256 + t];
    wb[0][IX(i, j)] = s * (1.f / NSAMP);
  }
  __syncthreads();
  if (w == 0) {
    float* E = wexp(&wb[0][0], &wb[0][MSZ], &wb[0][2 * MSZ], l);  // E = wb[0]+MSZ
    wmm(GsL, E, &wb[0][3 * MSZ], l);
    wmm(&wb[0][3 * MSZ], GsL, &wb[0][0], l);                       // mean
    wsym(&wb[0][0], l);
    wcpy(&wb[0][0], meanL, l);
  }
  __syncthreads();

  // --- E: wave0: W = invsqrt(mean) -> ws; wave1: geodesic -> out tail ---
  if (w == 0) {
    wcpy(meanL, &wb[0][0], l);
    float *S, *Z;
    wns(&wb[0][0], &wb[0][MSZ], &wb[0][2*MSZ], &wb[0][3*MSZ], &wb[2][0], l, &S, &Z);
    int i = l >> 2, j0 = (l & 3) << 2;
    *(float4*)&ws[WI_O + i * 16 + j0] = *(const float4*)&Z[IX(i, j0)];
  } else if (w == 1) {
    // newrm = Rs * (Ri*mean*Ri)^0.1 * Rs
    float* b0 = &wb[1][0];       float* b1 = &wb[1][MSZ];
    float* b2 = &wb[1][2 * MSZ]; float* b3 = &wb[1][3 * MSZ];
    wmm(RiL, meanL, b0, l);
    wmm(b0, RiL, b1, l);
    wsym(b1, l);
    float c = wtrace(b1) * (1.f / 16.f);
    wmad_diag(b1, 1.f / c, 0.f, l);     // P/c ~ I + E
    wlog(b1, b2, b0, b3, l);            // b2 = log(P/c)
    wmad_diag(b2, 0.1f, 0.f, l);        // K = 0.1*log
    float* E = wexp(b2, b0, b3, l);     // E = exp(K) in b0
    float s = expf(0.1f * logf(c));     // c^0.1
    wmad_diag(E, s, 0.f, l);
    wmm(RsL, E, b1, l);
    wmm(b1, RsL, b3, l);
    int i = l >> 2, j0 = (l & 3) << 2;
    *(float4*)&out[(size_t)NMAT * 256 + i * 16 + j0] = *(const float4*)&b3[IX(i, j0)];
  }
}

// Y = W * X * W, 4 matrices per block (one per wave). Pure streaming.
__global__ __launch_bounds__(256) void k_center(const float* __restrict__ X,
                                                const float* __restrict__ ws,
                                                float* __restrict__ out) {
  __shared__ __align__(16) float Wsm[MSZ];
  __shared__ __align__(16) float Xs[4 * MSZ];
  __shared__ __align__(16) float Ts[4 * MSZ];
  int t = threadIdx.x;
  long m0 = (long)blockIdx.x * 4;
  Wsm[(t >> 4) * ST + (t & 15)] = ws[WI_O + t];
  const float4* X4 = (const float4*)X;
  float4 xv = X4[m0 * 64 + t];
  int mw = t >> 6;            // matrix within block == wave id
  int l  = t & 63;
  int i  = l >> 2;
  int j0 = (l & 3) << 2;
  *(float4*)&Xs[mw * MSZ + i * ST + j0] = xv;
  __syncthreads();            // Wsm written by all 256 threads
  // phase 1: T = X * W   (per-wave private tile: wave-sync suffices below)
  float4 a = make_float4(0.f, 0.f, 0.f, 0.f);
  #pragma unroll
  for (int k = 0; k < 16; ++k) {
    float x = Xs[mw * MSZ + i * ST + k];
    const float4 wv = *(const float4*)&Wsm[k * ST + j0];
    a.x += x * wv.x; a.y += x * wv.y; a.z += x * wv.z; a.w += x * wv.w;
  }
  *(float4*)&Ts[mw * MSZ + i * ST + j0] = a;
  wsync();
  // phase 2: Y = W * T
  float4 y = make_float4(0.f, 0.f, 0.f, 0.f);
  #pragma unroll
  for (int k = 0; k < 16; ++k) {
    float w = Wsm[i * ST + k];
    const float4 tv = *(const float4*)&Ts[mw * MSZ + k * ST + j0];
    y.x += w * tv.x; y.y += w * tv.y; y.z += w * tv.z; y.w += w * tv.w;
  }
  ((float4*)out)[m0 * 64 + t] = y;
}

extern "C" void kernel_launch(void* const* d_in, const int* in_sizes, int n_in,
                              void* d_out, int out_size, void* d_ws, size_t ws_size,
                              hipStream_t stream) {
  (void)in_sizes; (void)n_in; (void)out_size; (void)ws_size;
  const float* X  = (const float*)d_in[0];
  const float* rm = (const float*)d_in[1];
  float* out = (float*)d_out;
  float* ws  = (float*)d_ws;

  k_part   <<<dim3(512),   dim3(512),  0, stream>>>(X, ws);
  k_mid    <<<dim3(1),     dim3(1024), 0, stream>>>(rm, ws, out);
  k_center <<<dim3(25600), dim3(256),  0, stream>>>(X, ws, out);
}

// Round 3
// 246.371 us; speedup vs baseline: 1.0063x; 1.0040x over previous
//
#include <hip/hip_runtime.h>
#include <math.h>

// Problem constants (N,T,V,M,n = 32,64,25,2,16)
#define NSAMP  32        // batch samples
#define BBATCH 3200      // matrices per sample (T*V*M)
#define NMAT   102400    // total matrices
#define ST     20        // LDS row stride: rows 16B-aligned, A-col reads 2-way banks (free)
#define IX(i,j) ((i)*ST+(j))
#define MSZ    (16*ST)

// workspace layout (float offsets)
#define PART_O 0         // 512*256 partial sums
#define WI_O   131072    // invsqrtm(mean) for centering

// Iteration counts. Spectra after trace-normalization are ~I +/- 0.03 here
// (means over 3200 matrices concentrate hard), so these have >=5x margin:
// NS residual 0.1 -> <1e-9 in 5 iters; log/exp Taylor err <= 0.1^8/8 ~ 1e-9.
#define NS_IT 5
#define LOG_M 7
#define EXP_M 6

// native 4-float vector for nontemporal builtins (HIP float4 is a class type)
typedef float nf4 __attribute__((ext_vector_type(4)));

// ---------------- wave-local 16x16 matrix helpers ----------------
// All helpers operate on ONE wave (64 lanes, lockstep). Lane l owns row
// i=l>>2, cols j0..j0+3 (j0=(l&3)*4). No __syncthreads: within a wave,
// cross-lane LDS visibility only needs the wave's own LDS ops drained.

__device__ __forceinline__ void wsync() {
  asm volatile("s_waitcnt lgkmcnt(0)" ::: "memory");
}

// C = A*B. C must not alias A or B.
__device__ __forceinline__ void wmm(const float* A, const float* B, float* C, int l) {
  int i = l >> 2, j0 = (l & 3) << 2;
  float4 acc = make_float4(0.f, 0.f, 0.f, 0.f);
  #pragma unroll
  for (int k = 0; k < 16; ++k) {
    float a = A[IX(i, k)];
    const float4 b = *(const float4*)&B[IX(k, j0)];
    acc.x += a * b.x; acc.y += a * b.y; acc.z += a * b.z; acc.w += a * b.w;
  }
  *(float4*)&C[IX(i, j0)] = acc;
  wsync();
}

// C = s*C + d*I  (per-lane read-modify-write, same address: in-order)
__device__ __forceinline__ void wmad_diag(float* C, float s, float d, int l) {
  int i = l >> 2, j0 = (l & 3) << 2;
  float4 p = *(float4*)&C[IX(i, j0)];
  p.x *= s; p.y *= s; p.z *= s; p.w *= s;
  if (i == j0) p.x += d; else if (i == j0 + 1) p.y += d;
  else if (i == j0 + 2) p.z += d; else if (i == j0 + 3) p.w += d;
  *(float4*)&C[IX(i, j0)] = p;
  wsync();
}

// C = d*I
__device__ __forceinline__ void wset_I(float* C, float d, int l) {
  int i = l >> 2, j0 = (l & 3) << 2;
  float4 p = make_float4(0.f, 0.f, 0.f, 0.f);
  if (i == j0) p.x = d; else if (i == j0 + 1) p.y = d;
  else if (i == j0 + 2) p.z = d; else if (i == j0 + 3) p.w = d;
  *(float4*)&C[IX(i, j0)] = p;
  wsync();
}

__device__ __forceinline__ void wsym(float* A, int l) {
  int i = l >> 2, j0 = (l & 3) << 2;
  float4 a = *(float4*)&A[IX(i, j0)];
  float4 v;
  v.x = 0.5f * (a.x + A[IX(j0,     i)]);
  v.y = 0.5f * (a.y + A[IX(j0 + 1, i)]);
  v.z = 0.5f * (a.z + A[IX(j0 + 2, i)]);
  v.w = 0.5f * (a.w + A[IX(j0 + 3, i)]);
  wsync();                              // all reads land before any write
  *(float4*)&A[IX(i, j0)] = v;
  wsync();
}

__device__ __forceinline__ float wtrace(const float* A) {
  float tr = 0.f;
  #pragma unroll
  for (int k = 0; k < 16; ++k) tr += A[IX(k, k)];
  return tr;
}

__device__ __forceinline__ void wcpy(const float* src, float* dst, int l) {
  int i = l >> 2, j0 = (l & 3) << 2;
  *(float4*)&dst[IX(i, j0)] = *(const float4*)&src[IX(i, j0)];
  wsync();
}

// Coupled Newton-Schulz sqrt/invsqrt. Input in Y0 (destroyed). 5 buffers.
__device__ void wns(float* Y0, float* Y1, float* Z0, float* Z1, float* P,
                    int l, float** pS, float** pZ) {
  float c = wtrace(Y0) * (1.f / 16.f);
  float ic = 1.f / c;
  int i = l >> 2, j0 = (l & 3) << 2;
  {
    float4 a = *(float4*)&Y0[IX(i, j0)];
    a.x *= ic; a.y *= ic; a.z *= ic; a.w *= ic;
    *(float4*)&Y0[IX(i, j0)] = a;
    float4 z = make_float4(0.f, 0.f, 0.f, 0.f);
    if (i == j0) z.x = 1.f; else if (i == j0 + 1) z.y = 1.f;
    else if (i == j0 + 2) z.z = 1.f; else if (i == j0 + 3) z.w = 1.f;
    *(float4*)&Z0[IX(i, j0)] = z;
  }
  wsync();
  float *Y = Y0, *Yn = Y1, *Z = Z0, *Zn = Z1;
  for (int it = 0; it < NS_IT; ++it) {
    wmm(Z, Y, P, l);                 // P = Z*Y
    wmad_diag(P, -0.5f, 1.5f, l);    // T = (3I - P)/2
    wmm(Y, P, Yn, l);
    wmm(P, Z, Zn, l);
    float* tp = Y; Y = Yn; Yn = tp;
    tp = Z; Z = Zn; Zn = tp;
  }
  float sc = sqrtf(c), isc = 1.f / sc;
  {
    float4 y = *(float4*)&Y[IX(i, j0)];
    y.x *= sc; y.y *= sc; y.z *= sc; y.w *= sc;
    *(float4*)&Y[IX(i, j0)] = y;
    float4 z = *(float4*)&Z[IX(i, j0)];
    z.x *= isc; z.y *= isc; z.z *= isc; z.w *= isc;
    *(float4*)&Z[IX(i, j0)] = z;
  }
  wsync();
  *pS = Y; *pZ = Z;
}

// L = log(S), S ~ I + E. S destroyed. L,R0,R1 distinct from S.
__device__ void wlog(float* S, float* L, float* R0, float* R1, int l) {
  wmad_diag(S, 1.f, -1.f, l);        // E = S - I
  float am = ((LOG_M & 1) ? 1.f : -1.f) / (float)LOG_M;
  wset_I(R0, am, l);
  float *R = R0, *Rn = R1;
  for (int j = LOG_M - 1; j >= 1; --j) {
    wmm(S, R, Rn, l);
    float aj = ((j & 1) ? 1.f : -1.f) / (float)j;
    wmad_diag(Rn, 1.f, aj, l);
    float* tp = R; R = Rn; Rn = tp;
  }
  wmm(S, R, L, l);
}

// exp(K), K preserved. Result lands in R0 (EXP_M even); returned by pointer.
__device__ float* wexp(const float* K, float* R0, float* R1, int l) {
  wset_I(R0, 1.f, l);
  float *R = R0, *Rn = R1;
  for (int j = EXP_M; j >= 1; --j) {
    wmm(K, R, Rn, l);
    wmad_diag(Rn, 1.f / (float)j, 1.f, l);
    float* tp = R; R = Rn; Rn = tp;
  }
  return R;
}

// Quad broadcast via DPP: every lane in a hardware quad gets lane (quad|Q)'s v.
template<int Q>
__device__ __forceinline__ float qb(float v) {
  return __int_as_float(__builtin_amdgcn_mov_dpp(
      __float_as_int(v), (Q | (Q << 2) | (Q << 4) | (Q << 6)), 0xF, 0xF, true));
}

// ---------------- kernels ----------------

// Partial sums: 512 blocks = 32 samples x 16 chunks of 200 matrices.
__global__ __launch_bounds__(512) void k_part(const float* __restrict__ X, float* __restrict__ ws) {
  int b = blockIdx.x >> 4;
  int c = blockIdx.x & 15;
  int t = threadIdx.x;
  int e4 = t & 63;
  int r  = t >> 6;                  // 0..7
  const float4* X4 = (const float4*)X;
  float4 s = make_float4(0.f, 0.f, 0.f, 0.f);
  long mbase = (long)b * BBATCH + c * 200;
  for (int i = r; i < 200; i += 8) {
    float4 v = X4[(mbase + i) * 64 + e4];
    s.x += v.x; s.y += v.y; s.z += v.z; s.w += v.w;
  }
  __shared__ float4 red[512];
  red[t] = s;
  __syncthreads();
  if (t < 64) {
    float4 o = red[t];
    #pragma unroll
    for (int k = 1; k < 8; ++k) {
      float4 v = red[t + 64 * k];
      o.x += v.x; o.y += v.y; o.z += v.z; o.w += v.w;
    }
    ((float4*)(ws + PART_O))[(long)blockIdx.x * 64 + t] = o;
  }
}

// Entire middle pipeline in ONE block. 16 waves; all cross-stage data in LDS.
__global__ __launch_bounds__(1024) void k_mid(const float* __restrict__ rm,
                                              float* __restrict__ ws,
                                              float* __restrict__ out) {
  __shared__ __align__(16) float XmL[NSAMP * 256];   // sample means, then log-maps
  __shared__ __align__(16) float wb[16][4 * MSZ];    // 4 strided buffers per wave
  __shared__ __align__(16) float GsL[MSZ], GiL[MSZ], RsL[MSZ], RiL[MSZ], meanL[MSZ];
  int t = threadIdx.x;
  int w = t >> 6, l = t & 63;

  // --- A: per-sample means from partial sums ---
  for (int idx = t; idx < NSAMP * 256; idx += 1024) {
    int b = idx >> 8, e = idx & 255;
    float s = 0.f;
    #pragma unroll
    for (int c = 0; c < 16; ++c) s += ws[PART_O + (b * 16 + c) * 256 + e];
    XmL[idx] = s * (1.f / BBATCH);
  }
  __syncthreads();

  // --- A2: G = mean_b(Xm) -> wb[0] (strided); rm -> wb[1] (strided) ---
  if (t < 256) {
    int i = t >> 4, j = t & 15;
    float s = 0.f;
    #pragma unroll
    for (int b = 0; b < NSAMP; ++b) s += XmL[b * 256 + t];
    wb[0][IX(i, j)] = s * (1.f / NSAMP);
  } else if (t < 512) {
    int e = t - 256, i = e >> 4, j = e & 15;
    wb[1][IX(i, j)] = rm[e];
  }
  __syncthreads();

  // --- B: NS(G) on wave0 and NS(rm) on wave1, concurrently ---
  if (w == 0) {
    float *S, *Z;
    wns(&wb[0][0], &wb[0][MSZ], &wb[0][2*MSZ], &wb[0][3*MSZ], &wb[2][0], l, &S, &Z);
    wcpy(S, GsL, l); wcpy(Z, GiL, l);
  } else if (w == 1) {
    float *S, *Z;
    wns(&wb[1][0], &wb[1][MSZ], &wb[1][2*MSZ], &wb[1][3*MSZ], &wb[3][0], l, &S, &Z);
    wcpy(S, RsL, l); wcpy(Z, RiL, l);
  }
  __syncthreads();

  // --- C: 32 log-maps, 16 waves x 2 rounds. L[b] overwrites XmL[b]. ---
  {
    float* B0 = &wb[w][0];       float* B1 = &wb[w][MSZ];
    float* B2 = &wb[w][2 * MSZ]; float* B3 = &wb[w][3 * MSZ];
    int i = l >> 2, j0 = (l & 3) << 2;
    for (int r = 0; r < 2; ++r) {
      int b = w + r * 16;
      *(float4*)&B0[IX(i, j0)] = *(const float4*)&XmL[b * 256 + i * 16 + j0];
      wsync();
      wmm(GiL, B0, B1, l);             // T = Gi*Xb
      wmm(B1, GiL, B2, l);             // S = Gi*Xb*Gi
      wsym(B2, l);
      wlog(B2, B3, B0, B1, l);         // L = B3 (S destroyed; B0,B1 scratch)
      *(float4*)&XmL[b * 256 + i * 16 + j0] = *(const float4*)&B3[IX(i, j0)];
      wsync();
    }
  }
  __syncthreads();

  // --- D: Lbar -> wb[0]; then mean = Gs*exp(Lbar)*Gs on wave0 ---
  if (t < 256) {
    int i = t >> 4, j = t & 15;
    float s = 0.f;
    #pragma unroll
    for (int b = 0; b < NSAMP; ++b) s += XmL[b * 256 + t];
    wb[0][IX(i, j)] = s * (1.f / NSAMP);
  }
  __syncthreads();
  if (w == 0) {
    float* E = wexp(&wb[0][0], &wb[0][MSZ], &wb[0][2 * MSZ], l);
    wmm(GsL, E, &wb[0][3 * MSZ], l);
    wmm(&wb[0][3 * MSZ], GsL, &wb[0][0], l);                       // mean
    wsym(&wb[0][0], l);
    wcpy(&wb[0][0], meanL, l);
  }
  __syncthreads();

  // --- E: wave0: W = invsqrt(mean) -> ws; wave1: geodesic -> out tail ---
  if (w == 0) {
    wcpy(meanL, &wb[0][0], l);
    float *S, *Z;
    wns(&wb[0][0], &wb[0][MSZ], &wb[0][2*MSZ], &wb[0][3*MSZ], &wb[2][0], l, &S, &Z);
    int i = l >> 2, j0 = (l & 3) << 2;
    *(float4*)&ws[WI_O + i * 16 + j0] = *(const float4*)&Z[IX(i, j0)];
  } else if (w == 1) {
    // newrm = Rs * (Ri*mean*Ri)^0.1 * Rs
    float* b0 = &wb[1][0];       float* b1 = &wb[1][MSZ];
    float* b2 = &wb[1][2 * MSZ]; float* b3 = &wb[1][3 * MSZ];
    wmm(RiL, meanL, b0, l);
    wmm(b0, RiL, b1, l);
    wsym(b1, l);
    float c = wtrace(b1) * (1.f / 16.f);
    wmad_diag(b1, 1.f / c, 0.f, l);     // P/c ~ I + E
    wlog(b1, b2, b0, b3, l);            // b2 = log(P/c)
    wmad_diag(b2, 0.1f, 0.f, l);        // K = 0.1*log
    float* E = wexp(b2, b0, b3, l);     // E = exp(K) in b0
    float s = expf(0.1f * logf(c));     // c^0.1
    wmad_diag(E, s, 0.f, l);
    wmm(RsL, E, b1, l);
    wmm(b1, RsL, b3, l);
    int i = l >> 2, j0 = (l & 3) << 2;
    *(float4*)&out[(size_t)NMAT * 256 + i * 16 + j0] = *(const float4*)&b3[IX(i, j0)];
  }
}

// Y = W X W, 4 matrices per block-round (1/wave), 8 rounds per block.
// W held in registers (w4 = W col-block for phase 2, wr = W row for phase 1);
// intermediate C = W*X passed through DPP quad-broadcast (no LDS).
#define ROUNDS 8
__global__ __launch_bounds__(256) void k_center(const float* __restrict__ X,
                                                const float* __restrict__ ws,
                                                float* __restrict__ out) {
  __shared__ __align__(16) float Wsm[MSZ];
  __shared__ __align__(16) float Xs[4 * MSZ];
  int t = threadIdx.x;
  int mw = t >> 6, l = t & 63;
  int i = l >> 2, j0 = (l & 3) << 2;
  Wsm[(t >> 4) * ST + (t & 15)] = ws[WI_O + t];
  __syncthreads();
  float4 w4[16];   // w4[k] = W(k, j0:j0+3)
  float  wr[16];   // wr[k] = W(i, k)
  #pragma unroll
  for (int k = 0; k < 16; ++k) {
    w4[k] = *(const float4*)&Wsm[IX(k, j0)];
    wr[k] = Wsm[IX(i, k)];
  }
  const float4* X4 = (const float4*)X;
  nf4* O4 = (nf4*)out;
  long gi = ((long)blockIdx.x * (4 * ROUNDS) + mw) * 64 + l;
  float4 xv = X4[gi];
  #pragma unroll
  for (int r = 0; r < ROUNDS; ++r) {
    *(float4*)&Xs[mw * MSZ + IX(i, j0)] = xv;      // stage this round's X tile
    if (r + 1 < ROUNDS) xv = X4[gi + 256 * (r + 1)];  // prefetch next (in flight over compute)
    wsync();
    // phase 1: tt(b) = C(i, j0+b), C = W*X  (broadcast b128 reads of X rows)
    float4 tt = make_float4(0.f, 0.f, 0.f, 0.f);
    #pragma unroll
    for (int k = 0; k < 16; ++k) {
      const float4 xk = *(const float4*)&Xs[mw * MSZ + IX(k, j0)];
      tt.x += wr[k] * xk.x; tt.y += wr[k] * xk.y;
      tt.z += wr[k] * xk.z; tt.w += wr[k] * xk.w;
    }
    // phase 2: y(b) = sum_k C(i,k) * W(k, j0+b); C-row gathered via quad DPP
    float4 y = make_float4(0.f, 0.f, 0.f, 0.f);
    #define PH2(Q) { \
      float c0 = qb<Q>(tt.x), c1 = qb<Q>(tt.y), c2 = qb<Q>(tt.z), c3 = qb<Q>(tt.w); \
      y.x += c0*w4[4*Q+0].x + c1*w4[4*Q+1].x + c2*w4[4*Q+2].x + c3*w4[4*Q+3].x; \
      y.y += c0*w4[4*Q+0].y + c1*w4[4*Q+1].y + c2*w4[4*Q+2].y + c3*w4[4*Q+3].y; \
      y.z += c0*w4[4*Q+0].z + c1*w4[4*Q+1].z + c2*w4[4*Q+2].z + c3*w4[4*Q+3].z; \
      y.w += c0*w4[4*Q+0].w + c1*w4[4*Q+1].w + c2*w4[4*Q+2].w + c3*w4[4*Q+3].w; }
    PH2(0) PH2(1) PH2(2) PH2(3)
    #undef PH2
    nf4 yv; yv.x = y.x; yv.y = y.y; yv.z = y.z; yv.w = y.w;
    __builtin_nontemporal_store(yv, &O4[gi + 256 * r]);
  }
}

extern "C" void kernel_launch(void* const* d_in, const int* in_sizes, int n_in,
                              void* d_out, int out_size, void* d_ws, size_t ws_size,
                              hipStream_t stream) {
  (void)in_sizes; (void)n_in; (void)out_size; (void)ws_size;
  const float* X  = (const float*)d_in[0];
  const float* rm = (const float*)d_in[1];
  float* out = (float*)d_out;
  float* ws  = (float*)d_ws;

  k_part   <<<dim3(512),  dim3(512),  0, stream>>>(X, ws);
  k_mid    <<<dim3(1),    dim3(1024), 0, stream>>>(rm, ws, out);
  k_center <<<dim3(3200), dim3(256),  0, stream>>>(X, ws, out);
}